// Round 2
// baseline (356.946 us; speedup 1.0000x reference)
//
#include <hip/hip_runtime.h>
#include <stdint.h>

#define NTOK 16384
#define HD   2048
#define ID   768
#define TOPK 8

typedef __bf16 bf16x8 __attribute__((ext_vector_type(8)));
typedef float  floatx4 __attribute__((ext_vector_type(4)));
typedef unsigned short ushort8 __attribute__((ext_vector_type(8)));

__device__ __forceinline__ unsigned short f32_to_bf16_rne(float f) {
    union { float f; uint32_t u; } v; v.f = f;
    uint32_t u = v.u;
    u += 0x7FFFu + ((u >> 16) & 1u);
    return (unsigned short)(u >> 16);
}
__device__ __forceinline__ float bf16_to_f32(unsigned short h) {
    union { uint32_t u; float f; } v; v.u = ((uint32_t)h) << 16;
    return v.f;
}

// async global->LDS, 16B/lane; LDS dest is wave-uniform base (HW adds lane*16)
#define GLD_LDS(gsrc, ldst)                                                              \
    __builtin_amdgcn_global_load_lds(                                                    \
        (const __attribute__((address_space(1))) uint32_t*)(const void*)(gsrc),          \
        (__attribute__((address_space(3))) uint32_t*)(void*)(ldst), 16, 0, 0)

// ---------------- w[k] = sum_j mask[j,k] * rw[k,j] ----------------
__global__ __launch_bounds__(256) void compute_w_kernel(const int* __restrict__ mask,
                                                        const float* __restrict__ rw,
                                                        float* __restrict__ w) {
    int k = blockIdx.x * 256 + threadIdx.x;
    if (k >= NTOK) return;
    float acc = 0.f;
#pragma unroll
    for (int j = 0; j < TOPK; ++j)
        acc += (float)mask[j * NTOK + k] * rw[k * TOPK + j];
    w[k] = acc;
}

// ---------------- fp32 -> bf16 (8 elems/thread) ----------------
__device__ __forceinline__ void cvt8(const float* __restrict__ src, unsigned short* __restrict__ dst,
                                     size_t i) {
    const float4* s = (const float4*)src;
    float4 a = s[2 * i], b = s[2 * i + 1];
    ushort8 o;
    o[0] = f32_to_bf16_rne(a.x); o[1] = f32_to_bf16_rne(a.y);
    o[2] = f32_to_bf16_rne(a.z); o[3] = f32_to_bf16_rne(a.w);
    o[4] = f32_to_bf16_rne(b.x); o[5] = f32_to_bf16_rne(b.y);
    o[6] = f32_to_bf16_rne(b.z); o[7] = f32_to_bf16_rne(b.w);
    *(ushort8*)(dst + 8 * i) = o;
}

__global__ __launch_bounds__(256) void convert_hs_kernel(const float* __restrict__ src,
                                                         unsigned short* __restrict__ dst) {
    size_t i = (size_t)blockIdx.x * 256 + threadIdx.x;   // NTOK*HD/8 groups
    cvt8(src, dst, i);
}

// gate, up, down weights (each ID*HD elems) -> one contiguous bf16 buffer
__global__ __launch_bounds__(256) void convert_w3_kernel(const float* __restrict__ g,
                                                         const float* __restrict__ u,
                                                         const float* __restrict__ d,
                                                         unsigned short* __restrict__ dst) {
    const int per = ID * HD / 8;                          // 196608
    int i = blockIdx.x * 256 + threadIdx.x;               // 0 .. 3*per-1
    int which = i / per;
    int off = i - which * per;
    const float* src = (which == 0) ? g : ((which == 1) ? u : d);
    // dst is contiguous across the three matrices
    const float4* s = (const float4*)src;
    float4 a = s[2 * (size_t)off], b = s[2 * (size_t)off + 1];
    ushort8 o;
    o[0] = f32_to_bf16_rne(a.x); o[1] = f32_to_bf16_rne(a.y);
    o[2] = f32_to_bf16_rne(a.z); o[3] = f32_to_bf16_rne(a.w);
    o[4] = f32_to_bf16_rne(b.x); o[5] = f32_to_bf16_rne(b.y);
    o[6] = f32_to_bf16_rne(b.z); o[7] = f32_to_bf16_rne(b.w);
    *(ushort8*)(dst + 8 * (size_t)i) = o;
}

// ---------------- swiglu: act[t,i] = silu(gu[t,i]) * gu[t,768+i] ----------------
__global__ __launch_bounds__(256) void swiglu_kernel(const unsigned short* __restrict__ gu,
                                                     unsigned short* __restrict__ act) {
    int i = blockIdx.x * 256 + threadIdx.x;   // 8-elem groups: NTOK * (ID/8)
    int t = i / (ID / 8);
    int c8 = i - t * (ID / 8);
    ushort8 g = *(const ushort8*)&gu[(size_t)t * (2 * ID) + c8 * 8];
    ushort8 u = *(const ushort8*)&gu[(size_t)t * (2 * ID) + ID + c8 * 8];
    ushort8 o;
#pragma unroll
    for (int j = 0; j < 8; ++j) {
        float gf = bf16_to_f32(g[j]);
        float uf = bf16_to_f32(u[j]);
        float s = gf / (1.f + __expf(-gf)) * uf;
        o[j] = f32_to_bf16_rne(s);
    }
    *(ushort8*)&act[(size_t)t * ID + c8 * 8] = o;
}

// ---------------- 256x256 counted-vmcnt deep-pipeline GEMM ----------------
// C = A[M,K] * B[NC,K]^T. BK=32, ring-4 LDS (depth-3 prefetch), 8 waves (2M x 4N),
// per-wave 128x64 output. Raw s_barrier + counted s_waitcnt vmcnt(12) keeps 3
// K-tiles of global_load_lds in flight across barriers (T3+T4).
template<int VM> __device__ __forceinline__ void wait_vm() {
    if constexpr (VM == 12)     asm volatile("s_waitcnt vmcnt(12)" ::: "memory");
    else if constexpr (VM == 8) asm volatile("s_waitcnt vmcnt(8)" ::: "memory");
    else if constexpr (VM == 4) asm volatile("s_waitcnt vmcnt(4)" ::: "memory");
    else                        asm volatile("s_waitcnt vmcnt(0)" ::: "memory");
}

template<int VM>
__device__ __forceinline__ void tile_body(const unsigned short* as, const unsigned short* bs,
                                          floatx4 (&acc)[8][4], int wr, int wc, int lane) {
    wait_vm<VM>();                       // tile's 4 loads landed (3 newer tiles in flight)
    __builtin_amdgcn_s_barrier();        // raw barrier: no vmcnt(0) drain
    asm volatile("" ::: "memory");
    bf16x8 af[8], bb[4];
    const int lrow = lane & 15;
    const int kg = (lane >> 4) * 8;
#pragma unroll
    for (int m = 0; m < 8; ++m)
        af[m] = *(const bf16x8*)&as[(wr * 128 + m * 16 + lrow) * 32 + kg];
#pragma unroll
    for (int n = 0; n < 4; ++n)
        bb[n] = *(const bf16x8*)&bs[(wc * 64 + n * 16 + lrow) * 32 + kg];
#pragma unroll
    for (int m = 0; m < 8; ++m)
#pragma unroll
        for (int n = 0; n < 4; ++n)
            acc[m][n] = __builtin_amdgcn_mfma_f32_16x16x32_bf16(af[m], bb[n], acc[m][n], 0, 0, 0);
    asm volatile("" ::: "memory");
    __builtin_amdgcn_s_barrier();        // all waves done reading this slot
    asm volatile("" ::: "memory");
}

template<int K, int NC, bool FUSE_DOWN>
__global__ __launch_bounds__(512, 2) void gemm256_kernel(
    const unsigned short* __restrict__ A,
    const unsigned short* __restrict__ B,
    unsigned short* __restrict__ Cb,
    const float* __restrict__ fin,
    const float* __restrict__ wtok,
    float* __restrict__ Cf,
    int nbx) {
    constexpr int NT = K / 32;
    static_assert(NT >= 4, "need >=4 K-tiles");
    __shared__ __align__(16) unsigned short As[4][256 * 32];
    __shared__ __align__(16) unsigned short Bs[4][256 * 32];

    // XCD-chunked block swizzle (grid % 8 == 0)
    const int bid = blockIdx.x;
    const int nwg = gridDim.x;
    const int nb  = (bid & 7) * (nwg >> 3) + (bid >> 3);
    const int bx = nb % nbx, by = nb / nbx;
    const int row0 = by * 256, col0 = bx * 256;

    const int tid = threadIdx.x;
    const int wid = tid >> 6, lane = tid & 63;
    const int wr = wid >> 2, wc = wid & 3;

    // staging: thread's LDS byte offsets o0/o1 map to (row r = o>>6, byte-col c = o&63)
    const int o0 = wid * 1024 + lane * 16;
    const int o1 = o0 + 8192;
    const unsigned short* srcA0 = A + (size_t)(row0 + (o0 >> 6)) * K + ((o0 & 63) >> 1);
    const unsigned short* srcA1 = A + (size_t)(row0 + (o1 >> 6)) * K + ((o1 & 63) >> 1);
    const unsigned short* srcB0 = B + (size_t)(col0 + (o0 >> 6)) * K + ((o0 & 63) >> 1);
    const unsigned short* srcB1 = B + (size_t)(col0 + (o1 >> 6)) * K + ((o1 & 63) >> 1);

#define STAGE(tt, s) do {                                        \
        GLD_LDS(srcA0 + (tt) * 32, &As[s][wid * 512]);           \
        GLD_LDS(srcA1 + (tt) * 32, &As[s][wid * 512 + 4096]);    \
        GLD_LDS(srcB0 + (tt) * 32, &Bs[s][wid * 512]);           \
        GLD_LDS(srcB1 + (tt) * 32, &Bs[s][wid * 512 + 4096]);    \
    } while (0)

    floatx4 acc[8][4];
#pragma unroll
    for (int m = 0; m < 8; ++m)
#pragma unroll
        for (int n = 0; n < 4; ++n) acc[m][n] = (floatx4){0.f, 0.f, 0.f, 0.f};

    // prologue: fill the ring
    STAGE(0, 0); STAGE(1, 1); STAGE(2, 2); STAGE(3, 3);

    for (int t = 0; t + 4 <= NT; ++t) {
        const int s = t & 3;
        tile_body<12>(&As[s][0], &Bs[s][0], acc, wr, wc, lane);
        if (t + 4 < NT) STAGE(t + 4, s);
    }
    tile_body<8>(&As[(NT - 3) & 3][0], &Bs[(NT - 3) & 3][0], acc, wr, wc, lane);
    tile_body<4>(&As[(NT - 2) & 3][0], &Bs[(NT - 2) & 3][0], acc, wr, wc, lane);
    tile_body<0>(&As[(NT - 1) & 3][0], &Bs[(NT - 1) & 3][0], acc, wr, wc, lane);
#undef STAGE

    // epilogue. D frag: col = lane&15, row = (lane>>4)*4 + r
    const int lrow = lane & 15, rg = (lane >> 4) * 4;
    if constexpr (!FUSE_DOWN) {
#pragma unroll
        for (int m = 0; m < 8; ++m)
#pragma unroll
            for (int r = 0; r < 4; ++r) {
                const int row = row0 + wr * 128 + m * 16 + rg + r;
#pragma unroll
                for (int n = 0; n < 4; ++n) {
                    const int col = col0 + wc * 64 + n * 16 + lrow;
                    Cb[(size_t)row * NC + col] = f32_to_bf16_rne(acc[m][n][r]);
                }
            }
    } else {
#pragma unroll
        for (int m = 0; m < 8; ++m)
#pragma unroll
            for (int r = 0; r < 4; ++r) {
                const int row = row0 + wr * 128 + m * 16 + rg + r;
                const float wv = wtok[row];
#pragma unroll
                for (int n = 0; n < 4; ++n) {
                    const int col = col0 + wc * 64 + n * 16 + lrow;
                    Cf[(size_t)row * NC + col] = fin[(size_t)row * NC + col] + wv * acc[m][n][r];
                }
            }
    }
}

extern "C" void kernel_launch(void* const* d_in, const int* in_sizes, int n_in,
                              void* d_out, int out_size, void* d_ws, size_t ws_size,
                              hipStream_t stream) {
    const float* hs   = (const float*)d_in[0];
    const int*   mask = (const int*)d_in[1];
    const float* rw   = (const float*)d_in[2];
    const float* fin  = (const float*)d_in[3];
    const float* gw   = (const float*)d_in[4];
    const float* uw   = (const float*)d_in[5];
    const float* dw   = (const float*)d_in[6];
    float* out = (float*)d_out;

    char* ws = (char*)d_ws;
    unsigned short* hs_b   = (unsigned short*)ws; ws += (size_t)NTOK * HD * 2;
    unsigned short* wcat_b = (unsigned short*)ws; ws += (size_t)3 * ID * HD * 2;  // gate|up|down
    unsigned short* gu_b   = (unsigned short*)ws; ws += (size_t)NTOK * 2 * ID * 2;
    float* wtok = (float*)ws;
    unsigned short* act_b = hs_b;              // reuse: hs_b dead after gemm_gu
    unsigned short* down_b = wcat_b + (size_t)2 * ID * HD;

    compute_w_kernel<<<NTOK / 256, 256, 0, stream>>>(mask, rw, wtok);
    convert_hs_kernel<<<(NTOK * HD / 8) / 256, 256, 0, stream>>>(hs, hs_b);
    convert_w3_kernel<<<(3 * ID * HD / 8) / 256, 256, 0, stream>>>(gw, uw, dw, wcat_b);

    // GU: C[16384,1536] = hs_b * [gate;up]^T  (K=2048), bf16 out
    gemm256_kernel<HD, 2 * ID, false><<<(NTOK / 256) * (2 * ID / 256), 512, 0, stream>>>(
        hs_b, wcat_b, gu_b, nullptr, nullptr, nullptr, 2 * ID / 256);

    swiglu_kernel<<<(NTOK * (ID / 8)) / 256, 256, 0, stream>>>(gu_b, act_b);

    // DOWN: out[16384,2048] = fin + w * (act * down^T)  (K=768), fp32 out
    gemm256_kernel<ID, HD, true><<<(NTOK / 256) * (HD / 256), 512, 0, stream>>>(
        act_b, down_b, nullptr, fin, wtok, out, HD / 256);
}

// Round 3
// 259.019 us; speedup vs baseline: 1.3781x; 1.3781x over previous
//
#include <hip/hip_runtime.h>
#include <stdint.h>

#define NTOK 16384
#define HD   2048
#define ID   768
#define TOPK 8

typedef __bf16 bf16x8 __attribute__((ext_vector_type(8)));
typedef float  floatx4 __attribute__((ext_vector_type(4)));
typedef unsigned short ushort8 __attribute__((ext_vector_type(8)));

__device__ __forceinline__ unsigned short f32_to_bf16_rne(float f) {
    union { float f; uint32_t u; } v; v.f = f;
    uint32_t u = v.u;
    u += 0x7FFFu + ((u >> 16) & 1u);
    return (unsigned short)(u >> 16);
}
__device__ __forceinline__ float bf16_to_f32(unsigned short h) {
    union { uint32_t u; float f; } v; v.u = ((uint32_t)h) << 16;
    return v.f;
}

// async global->LDS, 16B/lane; LDS dest is wave-uniform base (HW adds lane*16)
#define GLD_LDS(gsrc, ldst)                                                              \
    __builtin_amdgcn_global_load_lds(                                                    \
        (const __attribute__((address_space(1))) uint32_t*)(const void*)(gsrc),          \
        (__attribute__((address_space(3))) uint32_t*)(void*)(ldst), 16, 0, 0)

template<int VM> __device__ __forceinline__ void wait_vm() {
    if constexpr (VM == 4)      asm volatile("s_waitcnt vmcnt(4)" ::: "memory");
    else                        asm volatile("s_waitcnt vmcnt(0)" ::: "memory");
}
#define BARRIER() do { asm volatile("" ::: "memory");              \
                       __builtin_amdgcn_s_barrier();               \
                       asm volatile("" ::: "memory"); } while (0)

// ---------------- w[k] = sum_j mask[j,k] * rw[k,j] ----------------
__global__ __launch_bounds__(256) void compute_w_kernel(const int* __restrict__ mask,
                                                        const float* __restrict__ rw,
                                                        float* __restrict__ w) {
    int k = blockIdx.x * 256 + threadIdx.x;
    if (k >= NTOK) return;
    float acc = 0.f;
#pragma unroll
    for (int j = 0; j < TOPK; ++j)
        acc += (float)mask[j * NTOK + k] * rw[k * TOPK + j];
    w[k] = acc;
}

// ---------------- fp32 -> bf16 converts ----------------
__global__ __launch_bounds__(256) void convert_hs_kernel(const float* __restrict__ src,
                                                         unsigned short* __restrict__ dst) {
    size_t i = (size_t)blockIdx.x * 256 + threadIdx.x;
    const float4* s = (const float4*)src;
    float4 a = s[2 * i], b = s[2 * i + 1];
    ushort8 o;
    o[0] = f32_to_bf16_rne(a.x); o[1] = f32_to_bf16_rne(a.y);
    o[2] = f32_to_bf16_rne(a.z); o[3] = f32_to_bf16_rne(a.w);
    o[4] = f32_to_bf16_rne(b.x); o[5] = f32_to_bf16_rne(b.y);
    o[6] = f32_to_bf16_rne(b.z); o[7] = f32_to_bf16_rne(b.w);
    *(ushort8*)(dst + 8 * i) = o;
}

__global__ __launch_bounds__(256) void convert_w3_kernel(const float* __restrict__ g,
                                                         const float* __restrict__ u,
                                                         const float* __restrict__ d,
                                                         unsigned short* __restrict__ dst) {
    const int per = ID * HD / 8;
    int i = blockIdx.x * 256 + threadIdx.x;
    int which = i / per;
    int off = i - which * per;
    const float* src = (which == 0) ? g : ((which == 1) ? u : d);
    const float4* s = (const float4*)src;
    float4 a = s[2 * (size_t)off], b = s[2 * (size_t)off + 1];
    ushort8 o;
    o[0] = f32_to_bf16_rne(a.x); o[1] = f32_to_bf16_rne(a.y);
    o[2] = f32_to_bf16_rne(a.z); o[3] = f32_to_bf16_rne(a.w);
    o[4] = f32_to_bf16_rne(b.x); o[5] = f32_to_bf16_rne(b.y);
    o[6] = f32_to_bf16_rne(b.z); o[7] = f32_to_bf16_rne(b.w);
    *(ushort8*)(dst + 8 * (size_t)i) = o;
}

// ---------------- swiglu ----------------
__global__ __launch_bounds__(256) void swiglu_kernel(const unsigned short* __restrict__ gu,
                                                     unsigned short* __restrict__ act) {
    int i = blockIdx.x * 256 + threadIdx.x;
    int t = i / (ID / 8);
    int c8 = i - t * (ID / 8);
    ushort8 g = *(const ushort8*)&gu[(size_t)t * (2 * ID) + c8 * 8];
    ushort8 u = *(const ushort8*)&gu[(size_t)t * (2 * ID) + ID + c8 * 8];
    ushort8 o;
#pragma unroll
    for (int j = 0; j < 8; ++j) {
        float gf = bf16_to_f32(g[j]);
        float uf = bf16_to_f32(u[j]);
        float s = gf / (1.f + __expf(-gf)) * uf;
        o[j] = f32_to_bf16_rne(s);
    }
    *(ushort8*)&act[(size_t)t * ID + c8 * 8] = o;
}

// ---------------- 256x256 8-phase GEMM (T2 swizzle + T3/T4 counted vmcnt + T5) ----
// C = A[M,K]*B[NC,K]^T. BK=64 split as 2 k-slices; LDS regions per buf:
// 0:A-k0 1:B-k0 2:A-k1 3:B-k1, each [256 rows][32 elems] = 16 KB, XOR-swizzled.
template<int K, int NC, bool FUSE_DOWN>
__global__ __launch_bounds__(512, 2) void gemm8p_kernel(
    const unsigned short* __restrict__ A,
    const unsigned short* __restrict__ B,
    unsigned short* __restrict__ Cb,
    const float* __restrict__ fin,
    const float* __restrict__ wtok,
    float* __restrict__ Cf) {
    constexpr int NT = K / 64;
    static_assert(NT >= 2, "");
    __shared__ __align__(16) unsigned short lds[2][4][8192];

    // XCD-chunked swizzle (grid % 8 == 0), column-major tiles (B-panel L2 reuse)
    const int bid = blockIdx.x, nwg = gridDim.x;
    const int nb = (bid & 7) * (nwg >> 3) + (bid >> 3);
    const int bx = nb >> 6, by = nb & 63;           // M/256 == 64 for both GEMMs
    const int row0 = by * 256, col0 = bx * 256;

    const int tid = threadIdx.x, wid = tid >> 6, lane = tid & 63;
    const int wr = wid >> 2, wc = wid & 3;
    const int lrow = lane & 15, q = lane >> 4;
    const int rsw = (((lrow >> 1) & 3) ^ q) << 4;   // read-side swizzled 16B chunk

    // staging: thread covers LDS byte o = c*8192 + wid*1024 + lane*16 (linear dest).
    // source pre-swizzled: row = o>>6, kbyte = (o&63) ^ (((o>>7)&3)<<4)
    const int srow = wid * 16 + (lane >> 2);
    const int kswz = (((lane & 3) ^ ((lane >> 3) & 3)) << 3);   // elems
    const unsigned short* sA0 = A + (size_t)(row0 + srow) * K + kswz;
    const unsigned short* sA1 = A + (size_t)(row0 + 128 + srow) * K + kswz;
    const unsigned short* sB0 = B + (size_t)(col0 + srow) * K + kswz;
    const unsigned short* sB1 = B + (size_t)(col0 + 128 + srow) * K + kswz;

#define STAGE(sb, reg, p0, p1, koff) do {                                   \
        GLD_LDS((p0) + (koff), &lds[sb][reg][wid * 512]);                   \
        GLD_LDS((p1) + (koff), &lds[sb][reg][4096 + wid * 512]);            \
    } while (0)

#define READ_A(ks) do { const unsigned short* rgn = &lds[s][(ks) * 2][0];   \
        _Pragma("unroll")                                                   \
        for (int m = 0; m < 8; ++m) {                                       \
            const int rl = wr * 128 + m * 16 + lrow;                        \
            af[m] = *(const bf16x8*)((const char*)rgn + rl * 64 + rsw);     \
        } } while (0)

#define READ_B(ks, nh) do { const unsigned short* rgn = &lds[s][(ks) * 2 + 1][0]; \
        _Pragma("unroll")                                                   \
        for (int n = 0; n < 2; ++n) {                                       \
            const int rl = wc * 64 + (nh) * 32 + n * 16 + lrow;             \
            bb[n] = *(const bf16x8*)((const char*)rgn + rl * 64 + rsw);     \
        } } while (0)

#define MFMA_Q(nh) do {                                                     \
        __builtin_amdgcn_s_setprio(1);                                      \
        _Pragma("unroll")                                                   \
        for (int m = 0; m < 8; ++m) {                                       \
            acc[m][(nh) * 2 + 0] = __builtin_amdgcn_mfma_f32_16x16x32_bf16(af[m], bb[0], acc[m][(nh) * 2 + 0], 0, 0, 0); \
            acc[m][(nh) * 2 + 1] = __builtin_amdgcn_mfma_f32_16x16x32_bf16(af[m], bb[1], acc[m][(nh) * 2 + 1], 0, 0, 0); \
        }                                                                   \
        __builtin_amdgcn_s_setprio(0);                                      \
    } while (0)

    floatx4 acc[8][4];
#pragma unroll
    for (int m = 0; m < 8; ++m)
#pragma unroll
        for (int n = 0; n < 4; ++n) acc[m][n] = (floatx4){0.f, 0.f, 0.f, 0.f};
    bf16x8 af[8], bb[2];

    // prologue: tile 0 -> buf 0, in need-order A0,B0,A1,B1
    STAGE(0, 0, sA0, sA1, 0);
    STAGE(0, 1, sB0, sB1, 0);
    STAGE(0, 2, sA0, sA1, 32);
    STAGE(0, 3, sB0, sB1, 32);
    wait_vm<4>();            // A-k0, B-k0 of tile 0 landed
    BARRIER();

    for (int t = 0; t < NT - 1; ++t) {
        const int s = t & 1, sn = s ^ 1;
        const int ko = (t + 1) * 64;
        // P0: ks0/nh0, stage A-k0(t+1)
        READ_A(0); READ_B(0, 0);
        STAGE(sn, 0, sA0, sA1, ko);
        MFMA_Q(0);
        BARRIER();
        // P1: ks0/nh1, stage B-k0(t+1); wait A-k1,B-k1(t)
        READ_B(0, 1);
        STAGE(sn, 1, sB0, sB1, ko);
        MFMA_Q(1);
        wait_vm<4>();
        BARRIER();
        // P2: ks1/nh0, stage A-k1(t+1)
        READ_A(1); READ_B(1, 0);
        STAGE(sn, 2, sA0, sA1, ko + 32);
        MFMA_Q(0);
        BARRIER();
        // P3: ks1/nh1, stage B-k1(t+1); wait A-k0,B-k0(t+1)
        READ_B(1, 1);
        STAGE(sn, 3, sB0, sB1, ko + 32);
        MFMA_Q(1);
        wait_vm<4>();
        BARRIER();
    }
    {   // peeled final tile (no staging)
        const int s = (NT - 1) & 1;
        READ_A(0); READ_B(0, 0); MFMA_Q(0); BARRIER();
        READ_B(0, 1); MFMA_Q(1);
        wait_vm<0>();            // A-k1,B-k1 of final tile landed
        BARRIER();
        READ_A(1); READ_B(1, 0); MFMA_Q(0); BARRIER();
        READ_B(1, 1); MFMA_Q(1);
    }
#undef STAGE
#undef READ_A
#undef READ_B
#undef MFMA_Q

    // epilogue. D frag: col = lane&15, row = q*4 + r
    if constexpr (!FUSE_DOWN) {
#pragma unroll
        for (int m = 0; m < 8; ++m)
#pragma unroll
            for (int r = 0; r < 4; ++r) {
                const int row = row0 + wr * 128 + m * 16 + q * 4 + r;
#pragma unroll
                for (int n = 0; n < 4; ++n) {
                    const int col = col0 + wc * 64 + n * 16 + lrow;
                    Cb[(size_t)row * NC + col] = f32_to_bf16_rne(acc[m][n][r]);
                }
            }
    } else {
#pragma unroll
        for (int m = 0; m < 8; ++m)
#pragma unroll
            for (int r = 0; r < 4; ++r) {
                const int row = row0 + wr * 128 + m * 16 + q * 4 + r;
                const float wv = wtok[row];
#pragma unroll
                for (int n = 0; n < 4; ++n) {
                    const int col = col0 + wc * 64 + n * 16 + lrow;
                    Cf[(size_t)row * NC + col] = fin[(size_t)row * NC + col] + wv * acc[m][n][r];
                }
            }
    }
}

extern "C" void kernel_launch(void* const* d_in, const int* in_sizes, int n_in,
                              void* d_out, int out_size, void* d_ws, size_t ws_size,
                              hipStream_t stream) {
    const float* hs   = (const float*)d_in[0];
    const int*   mask = (const int*)d_in[1];
    const float* rw   = (const float*)d_in[2];
    const float* fin  = (const float*)d_in[3];
    const float* gw   = (const float*)d_in[4];
    const float* uw   = (const float*)d_in[5];
    const float* dw   = (const float*)d_in[6];
    float* out = (float*)d_out;

    char* ws = (char*)d_ws;
    unsigned short* hs_b   = (unsigned short*)ws; ws += (size_t)NTOK * HD * 2;
    unsigned short* wcat_b = (unsigned short*)ws; ws += (size_t)3 * ID * HD * 2;  // gate|up|down
    unsigned short* gu_b   = (unsigned short*)ws; ws += (size_t)NTOK * 2 * ID * 2;
    float* wtok = (float*)ws;
    unsigned short* act_b = hs_b;              // reuse: hs_b dead after gemm_gu
    unsigned short* down_b = wcat_b + (size_t)2 * ID * HD;

    compute_w_kernel<<<NTOK / 256, 256, 0, stream>>>(mask, rw, wtok);
    convert_hs_kernel<<<(NTOK * HD / 8) / 256, 256, 0, stream>>>(hs, hs_b);
    convert_w3_kernel<<<(3 * ID * HD / 8) / 256, 256, 0, stream>>>(gw, uw, dw, wcat_b);

    // GU: C[16384,1536] = hs_b * [gate;up]^T  (K=2048), bf16 out
    gemm8p_kernel<HD, 2 * ID, false><<<(NTOK / 256) * (2 * ID / 256), 512, 0, stream>>>(
        hs_b, wcat_b, gu_b, nullptr, nullptr, nullptr);

    swiglu_kernel<<<(NTOK * (ID / 8)) / 256, 256, 0, stream>>>(gu_b, act_b);

    // DOWN: out[16384,2048] = fin + w * (act * down^T)  (K=768), fp32 out
    gemm8p_kernel<ID, HD, true><<<(NTOK / 256) * (HD / 256), 512, 0, stream>>>(
        act_b, down_b, nullptr, fin, wtok, out);
}

// Round 4
// 243.174 us; speedup vs baseline: 1.4679x; 1.0652x over previous
//
#include <hip/hip_runtime.h>
#include <stdint.h>

#define NTOK 16384
#define HD   2048
#define ID   768
#define TOPK 8

typedef __bf16 bf16x8 __attribute__((ext_vector_type(8)));
typedef float  floatx4 __attribute__((ext_vector_type(4)));
typedef unsigned short ushort8 __attribute__((ext_vector_type(8)));

__device__ __forceinline__ unsigned short f32_to_bf16_rne(float f) {
    union { float f; uint32_t u; } v; v.f = f;
    uint32_t u = v.u;
    u += 0x7FFFu + ((u >> 16) & 1u);
    return (unsigned short)(u >> 16);
}
__device__ __forceinline__ float bf16_to_f32(unsigned short h) {
    union { uint32_t u; float f; } v; v.u = ((uint32_t)h) << 16;
    return v.f;
}

// async global->LDS, 16B/lane; LDS dest is wave-uniform base (HW adds lane*16)
#define GLD_LDS(gsrc, ldst)                                                              \
    __builtin_amdgcn_global_load_lds(                                                    \
        (const __attribute__((address_space(1))) uint32_t*)(const void*)(gsrc),          \
        (__attribute__((address_space(3))) uint32_t*)(void*)(ldst), 16, 0, 0)

template<int VM> __device__ __forceinline__ void wait_vm() {
    if constexpr (VM == 4)      asm volatile("s_waitcnt vmcnt(4)" ::: "memory");
    else if constexpr (VM == 3) asm volatile("s_waitcnt vmcnt(3)" ::: "memory");
    else                        asm volatile("s_waitcnt vmcnt(0)" ::: "memory");
}
#define BARRIER() do { asm volatile("" ::: "memory");              \
                       __builtin_amdgcn_s_barrier();               \
                       asm volatile("" ::: "memory"); } while (0)

// ---------------- w[k] = sum_j mask[j,k] * rw[k,j] ----------------
__global__ __launch_bounds__(256) void compute_w_kernel(const int* __restrict__ mask,
                                                        const float* __restrict__ rw,
                                                        float* __restrict__ w) {
    int k = blockIdx.x * 256 + threadIdx.x;
    if (k >= NTOK) return;
    float acc = 0.f;
#pragma unroll
    for (int j = 0; j < TOPK; ++j)
        acc += (float)mask[j * NTOK + k] * rw[k * TOPK + j];
    w[k] = acc;
}

// ---------------- fp32 -> bf16 converts ----------------
__global__ __launch_bounds__(256) void convert_hs_kernel(const float* __restrict__ src,
                                                         unsigned short* __restrict__ dst) {
    size_t i = (size_t)blockIdx.x * 256 + threadIdx.x;
    const float4* s = (const float4*)src;
    float4 a = s[2 * i], b = s[2 * i + 1];
    ushort8 o;
    o[0] = f32_to_bf16_rne(a.x); o[1] = f32_to_bf16_rne(a.y);
    o[2] = f32_to_bf16_rne(a.z); o[3] = f32_to_bf16_rne(a.w);
    o[4] = f32_to_bf16_rne(b.x); o[5] = f32_to_bf16_rne(b.y);
    o[6] = f32_to_bf16_rne(b.z); o[7] = f32_to_bf16_rne(b.w);
    *(ushort8*)(dst + 8 * i) = o;
}

__global__ __launch_bounds__(256) void convert_w3_kernel(const float* __restrict__ g,
                                                         const float* __restrict__ u,
                                                         const float* __restrict__ d,
                                                         unsigned short* __restrict__ dst) {
    const int per = ID * HD / 8;
    int i = blockIdx.x * 256 + threadIdx.x;
    int which = i / per;
    int off = i - which * per;
    const float* src = (which == 0) ? g : ((which == 1) ? u : d);
    const float4* s = (const float4*)src;
    float4 a = s[2 * (size_t)off], b = s[2 * (size_t)off + 1];
    ushort8 o;
    o[0] = f32_to_bf16_rne(a.x); o[1] = f32_to_bf16_rne(a.y);
    o[2] = f32_to_bf16_rne(a.z); o[3] = f32_to_bf16_rne(a.w);
    o[4] = f32_to_bf16_rne(b.x); o[5] = f32_to_bf16_rne(b.y);
    o[6] = f32_to_bf16_rne(b.z); o[7] = f32_to_bf16_rne(b.w);
    *(ushort8*)(dst + 8 * (size_t)i) = o;
}

// ---------------- swiglu ----------------
__global__ __launch_bounds__(256) void swiglu_kernel(const unsigned short* __restrict__ gu,
                                                     unsigned short* __restrict__ act) {
    int i = blockIdx.x * 256 + threadIdx.x;
    int t = i / (ID / 8);
    int c8 = i - t * (ID / 8);
    ushort8 g = *(const ushort8*)&gu[(size_t)t * (2 * ID) + c8 * 8];
    ushort8 u = *(const ushort8*)&gu[(size_t)t * (2 * ID) + ID + c8 * 8];
    ushort8 o;
#pragma unroll
    for (int j = 0; j < 8; ++j) {
        float gf = bf16_to_f32(g[j]);
        float uf = bf16_to_f32(u[j]);
        float s = gf / (1.f + __expf(-gf)) * uf;
        o[j] = f32_to_bf16_rne(s);
    }
    *(ushort8*)&act[(size_t)t * ID + c8 * 8] = o;
}

// ================= GU GEMM: 256x192 tile, BK=64, zero-tail grid =================
// C[NTOK,1536] = A[NTOK,HD] * B[1536,HD]^T. 512 blocks = exactly 2 rounds @1 blk/CU.
// LDS per buf: A-k0[16K] A-k1[16K] B-k0[12K] B-k1[12K] = 56KB; 2 bufs = 112KB.
// 8 waves 2Mx4N, per-wave 128x48 (acc 8x3). Counted vmcnt(4)@P1 / vmcnt(3)@P3.
__global__ __launch_bounds__(512, 1) void gemm_gu_kernel(
    const unsigned short* __restrict__ A,
    const unsigned short* __restrict__ B,
    unsigned short* __restrict__ Cb) {
    constexpr int K = HD;          // 2048
    constexpr int NT = K / 64;     // 32
    __shared__ __align__(16) unsigned char lds[2][57344];

    const int bid = blockIdx.x, nwg = gridDim.x;          // 512
    const int nb = (bid & 7) * (nwg >> 3) + (bid >> 3);   // XCD-chunked
    const int bx = nb & 7, by = nb >> 3;                  // row-major: A-panel reuse
    const int row0 = by * 256, col0 = bx * 192;

    const int tid = threadIdx.x, wid = tid >> 6, lane = tid & 63;
    const int wr = wid >> 2, wc = wid & 3;
    const int lrow = lane & 15, q = lane >> 4;
    const int rsw = ((q ^ ((lrow >> 1) & 3)) << 4);       // read-side swizzle (bytes)

    // staging sources; swizzle key (row>>1)&3 == (lane>>3)&3 on all paths
    const int kswz = (((lane & 3) ^ ((lane >> 3) & 3)) << 3);   // elems
    const unsigned short* sA[2];
#pragma unroll
    for (int h = 0; h < 2; ++h) {
        const int o = h * 8192 + wid * 1024 + lane * 16;
        sA[h] = A + (size_t)(row0 + (o >> 6)) * K + kswz;
    }
    const unsigned short* sB[3];
#pragma unroll
    for (int r = 0; r < 3; ++r) {
        const int o = r * 8192 + tid * 16;
        const int ks = (o >= 12288) ? 1 : 0;
        const int brow = (o - ks * 12288) >> 6;
        sB[r] = B + (size_t)(col0 + brow) * K + ks * 32 + kswz;
    }

#define STAGE_A(sb, ks, kt) do {                                                            \
        GLD_LDS(sA[0] + (kt) * 64 + (ks) * 32, lds[sb] + (ks) * 16384 + wid * 1024);        \
        GLD_LDS(sA[1] + (kt) * 64 + (ks) * 32, lds[sb] + (ks) * 16384 + 8192 + wid * 1024); \
    } while (0)
#define STAGE_B01(sb, kt) do {                                                              \
        GLD_LDS(sB[0] + (kt) * 64, lds[sb] + 32768 + wid * 1024);                           \
        GLD_LDS(sB[1] + (kt) * 64, lds[sb] + 32768 + 8192 + wid * 1024);                    \
    } while (0)
#define STAGE_B2(sb, kt)                                                                    \
        GLD_LDS(sB[2] + (kt) * 64, lds[sb] + 32768 + 16384 + wid * 1024)

#define READ_A(s, ks) do { const unsigned char* rgn = lds[s] + (ks) * 16384;                \
        _Pragma("unroll")                                                                   \
        for (int m = 0; m < 8; ++m)                                                         \
            af[m] = *(const bf16x8*)(rgn + (wr * 128 + m * 16 + lrow) * 64 + rsw);          \
    } while (0)
#define READ_B(s, ks) do { const unsigned char* rgn = lds[s] + 32768 + (ks) * 12288;        \
        _Pragma("unroll")                                                                   \
        for (int n = 0; n < 3; ++n)                                                         \
            bb[n] = *(const bf16x8*)(rgn + (wc * 48 + n * 16 + lrow) * 64 + rsw);           \
    } while (0)
#define MFMA_H(mh) do {                                                                     \
        __builtin_amdgcn_s_setprio(1);                                                      \
        _Pragma("unroll")                                                                   \
        for (int m = (mh) * 4; m < (mh) * 4 + 4; ++m)                                       \
            _Pragma("unroll")                                                               \
            for (int n = 0; n < 3; ++n)                                                     \
                acc[m][n] = __builtin_amdgcn_mfma_f32_16x16x32_bf16(af[m], bb[n], acc[m][n], 0, 0, 0); \
        __builtin_amdgcn_s_setprio(0);                                                      \
    } while (0)

    floatx4 acc[8][3];
#pragma unroll
    for (int m = 0; m < 8; ++m)
#pragma unroll
        for (int n = 0; n < 3; ++n) acc[m][n] = (floatx4){0.f, 0.f, 0.f, 0.f};
    bf16x8 af[8], bb[3];

    // prologue: tile 0 (issue order: A-k0[2], B01[2], A-k1[2], B2[1])
    STAGE_A(0, 0, 0);
    STAGE_B01(0, 0);
    STAGE_A(0, 1, 0);
    STAGE_B2(0, 0);
    wait_vm<3>();          // A-k0 + B-rounds-01 landed; A-k1,B2 still in flight
    BARRIER();

    for (int t = 0; t < NT - 1; ++t) {
        const int s = t & 1, sn = s ^ 1;
        // P0: compute k0 (m-half 0); prefetch A-k0(t+1)
        READ_A(s, 0); READ_B(s, 0);
        STAGE_A(sn, 0, t + 1);
        MFMA_H(0);
        BARRIER();
        // P1: compute k0 (m-half 1); prefetch B01(t+1); land A-k1(t),B2(t)
        STAGE_B01(sn, t + 1);
        MFMA_H(1);
        wait_vm<4>();
        BARRIER();
        // P2: compute k1 (m-half 0); prefetch A-k1(t+1)
        READ_A(s, 1); READ_B(s, 1);
        STAGE_A(sn, 1, t + 1);
        MFMA_H(0);
        BARRIER();
        // P3: compute k1 (m-half 1); prefetch B2(t+1); land A-k0(t+1),B01(t+1)
        STAGE_B2(sn, t + 1);
        MFMA_H(1);
        wait_vm<3>();
        BARRIER();
    }
    {   // peeled final tile
        const int s = (NT - 1) & 1;
        READ_A(s, 0); READ_B(s, 0);
        MFMA_H(0);
        BARRIER();
        MFMA_H(1);
        wait_vm<0>();      // A-k1,B2 of final tile landed
        BARRIER();
        READ_A(s, 1); READ_B(s, 1);
        MFMA_H(0);
        MFMA_H(1);
    }
#undef STAGE_A
#undef STAGE_B01
#undef STAGE_B2
#undef READ_A
#undef READ_B
#undef MFMA_H

    // epilogue. D frag: col = lane&15, row = q*4 + r
#pragma unroll
    for (int m = 0; m < 8; ++m)
#pragma unroll
        for (int r = 0; r < 4; ++r) {
            const int row = row0 + wr * 128 + m * 16 + q * 4 + r;
#pragma unroll
            for (int n = 0; n < 3; ++n) {
                const int col = col0 + wc * 48 + n * 16 + lrow;
                Cb[(size_t)row * (2 * ID) + col] = f32_to_bf16_rne(acc[m][n][r]);
            }
        }
}

// ---------------- 256x256 8-phase GEMM (down projection, unchanged r3) ----------
template<int K, int NC, bool FUSE_DOWN>
__global__ __launch_bounds__(512, 2) void gemm8p_kernel(
    const unsigned short* __restrict__ A,
    const unsigned short* __restrict__ B,
    unsigned short* __restrict__ Cb,
    const float* __restrict__ fin,
    const float* __restrict__ wtok,
    float* __restrict__ Cf) {
    constexpr int NT = K / 64;
    static_assert(NT >= 2, "");
    __shared__ __align__(16) unsigned short lds[2][4][8192];

    const int bid = blockIdx.x, nwg = gridDim.x;
    const int nb = (bid & 7) * (nwg >> 3) + (bid >> 3);
    const int bx = nb >> 6, by = nb & 63;
    const int row0 = by * 256, col0 = bx * 256;

    const int tid = threadIdx.x, wid = tid >> 6, lane = tid & 63;
    const int wr = wid >> 2, wc = wid & 3;
    const int lrow = lane & 15, q = lane >> 4;
    const int rsw = (((lrow >> 1) & 3) ^ q) << 4;

    const int srow = wid * 16 + (lane >> 2);
    const int kswz = (((lane & 3) ^ ((lane >> 3) & 3)) << 3);
    const unsigned short* sA0 = A + (size_t)(row0 + srow) * K + kswz;
    const unsigned short* sA1 = A + (size_t)(row0 + 128 + srow) * K + kswz;
    const unsigned short* sB0 = B + (size_t)(col0 + srow) * K + kswz;
    const unsigned short* sB1 = B + (size_t)(col0 + 128 + srow) * K + kswz;

#define STAGE(sb, reg, p0, p1, koff) do {                                   \
        GLD_LDS((p0) + (koff), &lds[sb][reg][wid * 512]);                   \
        GLD_LDS((p1) + (koff), &lds[sb][reg][4096 + wid * 512]);            \
    } while (0)

#define READ_A(ks) do { const unsigned short* rgn = &lds[s][(ks) * 2][0];   \
        _Pragma("unroll")                                                   \
        for (int m = 0; m < 8; ++m) {                                       \
            const int rl = wr * 128 + m * 16 + lrow;                        \
            af[m] = *(const bf16x8*)((const char*)rgn + rl * 64 + rsw);     \
        } } while (0)

#define READ_B(ks, nh) do { const unsigned short* rgn = &lds[s][(ks) * 2 + 1][0]; \
        _Pragma("unroll")                                                   \
        for (int n = 0; n < 2; ++n) {                                       \
            const int rl = wc * 64 + (nh) * 32 + n * 16 + lrow;             \
            bb[n] = *(const bf16x8*)((const char*)rgn + rl * 64 + rsw);     \
        } } while (0)

#define MFMA_Q(nh) do {                                                     \
        __builtin_amdgcn_s_setprio(1);                                      \
        _Pragma("unroll")                                                   \
        for (int m = 0; m < 8; ++m) {                                       \
            acc[m][(nh) * 2 + 0] = __builtin_amdgcn_mfma_f32_16x16x32_bf16(af[m], bb[0], acc[m][(nh) * 2 + 0], 0, 0, 0); \
            acc[m][(nh) * 2 + 1] = __builtin_amdgcn_mfma_f32_16x16x32_bf16(af[m], bb[1], acc[m][(nh) * 2 + 1], 0, 0, 0); \
        }                                                                   \
        __builtin_amdgcn_s_setprio(0);                                      \
    } while (0)

    floatx4 acc[8][4];
#pragma unroll
    for (int m = 0; m < 8; ++m)
#pragma unroll
        for (int n = 0; n < 4; ++n) acc[m][n] = (floatx4){0.f, 0.f, 0.f, 0.f};
    bf16x8 af[8], bb[2];

    STAGE(0, 0, sA0, sA1, 0);
    STAGE(0, 1, sB0, sB1, 0);
    STAGE(0, 2, sA0, sA1, 32);
    STAGE(0, 3, sB0, sB1, 32);
    wait_vm<4>();
    BARRIER();

    for (int t = 0; t < NT - 1; ++t) {
        const int s = t & 1, sn = s ^ 1;
        const int ko = (t + 1) * 64;
        READ_A(0); READ_B(0, 0);
        STAGE(sn, 0, sA0, sA1, ko);
        MFMA_Q(0);
        BARRIER();
        READ_B(0, 1);
        STAGE(sn, 1, sB0, sB1, ko);
        MFMA_Q(1);
        wait_vm<4>();
        BARRIER();
        READ_A(1); READ_B(1, 0);
        STAGE(sn, 2, sA0, sA1, ko + 32);
        MFMA_Q(0);
        BARRIER();
        READ_B(1, 1);
        STAGE(sn, 3, sB0, sB1, ko + 32);
        MFMA_Q(1);
        wait_vm<4>();
        BARRIER();
    }
    {
        const int s = (NT - 1) & 1;
        READ_A(0); READ_B(0, 0); MFMA_Q(0); BARRIER();
        READ_B(0, 1); MFMA_Q(1);
        wait_vm<0>();
        BARRIER();
        READ_A(1); READ_B(1, 0); MFMA_Q(0); BARRIER();
        READ_B(1, 1); MFMA_Q(1);
    }
#undef STAGE
#undef READ_A
#undef READ_B
#undef MFMA_Q

    if constexpr (!FUSE_DOWN) {
#pragma unroll
        for (int m = 0; m < 8; ++m)
#pragma unroll
            for (int r = 0; r < 4; ++r) {
                const int row = row0 + wr * 128 + m * 16 + q * 4 + r;
#pragma unroll
                for (int n = 0; n < 4; ++n) {
                    const int col = col0 + wc * 64 + n * 16 + lrow;
                    Cb[(size_t)row * NC + col] = f32_to_bf16_rne(acc[m][n][r]);
                }
            }
    } else {
#pragma unroll
        for (int m = 0; m < 8; ++m)
#pragma unroll
            for (int r = 0; r < 4; ++r) {
                const int row = row0 + wr * 128 + m * 16 + q * 4 + r;
                const float wv = wtok[row];
#pragma unroll
                for (int n = 0; n < 4; ++n) {
                    const int col = col0 + wc * 64 + n * 16 + lrow;
                    Cf[(size_t)row * NC + col] = fin[(size_t)row * NC + col] + wv * acc[m][n][r];
                }
            }
    }
}

extern "C" void kernel_launch(void* const* d_in, const int* in_sizes, int n_in,
                              void* d_out, int out_size, void* d_ws, size_t ws_size,
                              hipStream_t stream) {
    const float* hs   = (const float*)d_in[0];
    const int*   mask = (const int*)d_in[1];
    const float* rw   = (const float*)d_in[2];
    const float* fin  = (const float*)d_in[3];
    const float* gw   = (const float*)d_in[4];
    const float* uw   = (const float*)d_in[5];
    const float* dw   = (const float*)d_in[6];
    float* out = (float*)d_out;

    char* ws = (char*)d_ws;
    unsigned short* hs_b   = (unsigned short*)ws; ws += (size_t)NTOK * HD * 2;
    unsigned short* wcat_b = (unsigned short*)ws; ws += (size_t)3 * ID * HD * 2;  // gate|up|down
    unsigned short* gu_b   = (unsigned short*)ws; ws += (size_t)NTOK * 2 * ID * 2;
    float* wtok = (float*)ws;
    unsigned short* act_b = hs_b;              // reuse: hs_b dead after gemm_gu
    unsigned short* down_b = wcat_b + (size_t)2 * ID * HD;

    compute_w_kernel<<<NTOK / 256, 256, 0, stream>>>(mask, rw, wtok);
    convert_hs_kernel<<<(NTOK * HD / 8) / 256, 256, 0, stream>>>(hs, hs_b);
    convert_w3_kernel<<<(3 * ID * HD / 8) / 256, 256, 0, stream>>>(gw, uw, dw, wcat_b);

    // GU: C[16384,1536] = hs_b * [gate;up]^T (K=2048), 256x192 tiles, 512 blocks
    gemm_gu_kernel<<<512, 512, 0, stream>>>(hs_b, wcat_b, gu_b);

    swiglu_kernel<<<(NTOK * (ID / 8)) / 256, 256, 0, stream>>>(gu_b, act_b);

    // DOWN: out[16384,2048] = fin + w * (act * down^T) (K=768), fp32 out
    gemm8p_kernel<ID, HD, true><<<(NTOK / 256) * (HD / 256), 512, 0, stream>>>(
        act_b, down_b, nullptr, fin, wtok, out);
}